// Round 17
// baseline (153.693 us; speedup 1.0000x reference)
//
#include <hip/hip_runtime.h>
#include <hip/hip_bf16.h>
#include <math.h>

typedef __attribute__((ext_vector_type(8))) __bf16 bf16x8;
typedef __attribute__((ext_vector_type(4))) __bf16 bf16x4;
typedef __attribute__((ext_vector_type(4))) float f32x4;

#define DEVINL static __device__ __forceinline__

static constexpr int Tlen = 1024;
static constexpr int HD = 32;

DEVINL void gload_lds16(const void* g, void* l) {
  __builtin_amdgcn_global_load_lds(
      (const __attribute__((address_space(1))) void*)g,
      (__attribute__((address_space(3))) void*)l, 16, 0, 0);
}

DEVINL unsigned short bfbits(float x) {
  __bf16 b = (__bf16)x;
  return __builtin_bit_cast(unsigned short, b);
}

// ---------- fused staging kernel: cvt | transpose(w_attn) | transpose(w_proj) | sincos ----
__global__ void k_stage(const float* __restrict__ x, __bf16* __restrict__ xb,
                        const float* __restrict__ w_attn, __bf16* __restrict__ waT,
                        const float* __restrict__ w_proj, __bf16* __restrict__ wpT,
                        const float* __restrict__ pos, float* __restrict__ cosT,
                        float* __restrict__ sinT) {
  const int bid = blockIdx.x;
  if (bid < 2048) {
    int i = (bid * 256 + threadIdx.x) * 8;
    const float4* p = (const float4*)(x + i);
    float4 a = p[0], b = p[1];
    bf16x8 v;
    v[0] = (__bf16)a.x; v[1] = (__bf16)a.y; v[2] = (__bf16)a.z; v[3] = (__bf16)a.w;
    v[4] = (__bf16)b.x; v[5] = (__bf16)b.y; v[6] = (__bf16)b.z; v[7] = (__bf16)b.w;
    *(bf16x8*)(xb + i) = v;
    return;
  }
  if (bid >= 6144) {
    int idx = (bid - 6144) * 256 + threadIdx.x;  // T*32
    int t = idx >> 5, d = idx & 31;
    float invf = powf(10000.0f, -(float)d * (1.0f / 32.0f));
    float ang = pos[t] * invf;
    cosT[idx] = cosf(ang);
    sinT[idx] = sinf(ang);
    return;
  }
  const float* w;
  __bf16* wt;
  int n0, k0, K, N;
  if (bid < 5120) {  // w_attn: 3072 blocks
    int t = bid - 2048;
    w = w_attn; wt = waT; K = 2048; N = 6144;
    n0 = (t % 96) * 64; k0 = (t / 96) * 64;
  } else {           // w_proj: 1024 blocks
    int t = bid - 5120;
    w = w_proj; wt = wpT; K = 2048; N = 2048;
    n0 = (t % 32) * 64; k0 = (t / 32) * 64;
  }
  __shared__ float tile[64][65];
  const int tx = threadIdx.x & 15;
  const int ty = threadIdx.x >> 4;
#pragma unroll
  for (int i = 0; i < 4; ++i) {
    float4 v = *(const float4*)&w[(size_t)(k0 + ty + i * 16) * N + n0 + tx * 4];
    tile[ty + i * 16][tx * 4 + 0] = v.x;
    tile[ty + i * 16][tx * 4 + 1] = v.y;
    tile[ty + i * 16][tx * 4 + 2] = v.z;
    tile[ty + i * 16][tx * 4 + 3] = v.w;
  }
  __syncthreads();
#pragma unroll
  for (int i = 0; i < 4; ++i) {
    int n = ty + i * 16;
    bf16x4 s;
#pragma unroll
    for (int j = 0; j < 4; ++j) s[j] = (__bf16)tile[tx * 4 + j][n];
    *(bf16x4*)&wt[(size_t)(n0 + n) * K + k0 + tx * 4] = s;
  }
}

// ---------- 2-phase dbuf GEMM template (counted vmcnt, chunk swizzle) ----------
// MODE 0: fp32 store, tswz 2D-grid mapping.
// MODE 1: RoPE epilogue, 1D grid of 512. MODE 2: fp32 store, 1D grid of 512.
// R17 change (MODE 1/2): per-XCD 8x8 block square. Grid = 16 by x 32 bx; the
// whole grid is co-resident (2 blocks/CU), so each XCD permanently hosts 64
// blocks. by-pair clustering gave 2 A-panels + 32 B-panels = 25 MB per XCD
// (L2 = 4 MB -> B thrash, FETCH 102 MB vs 33 MB ideal). 8x8 square = 8 A +
// 8 B panels = 10 MB, per-K-step sliver set 320 KB -> larger drift tolerance.
template <int BM, int BN, int WM, int WN, int MODE>
__launch_bounds__(WM * WN * 64, 4)
__global__ void k_gemm(const __bf16* __restrict__ A, const __bf16* __restrict__ Bt,
                       int M, int N, int K, float* __restrict__ Cout,
                       __bf16* __restrict__ Qo, __bf16* __restrict__ Ko,
                       __bf16* __restrict__ Vto, const float* __restrict__ cosT,
                       const float* __restrict__ sinT) {
  constexpr int T = WM * WN * 64;
  constexpr int M_rep = BM / (WM * 16);
  constexpr int N_rep = BN / (WN * 16);
  constexpr int nA = (BM * 128) / (T * 16);
  constexpr int nB = (BN * 128) / (T * 16);
  constexpr int NISSUE = nA + nB;
  constexpr int ROWS_PER_ISSUE = T / 8;

  __shared__ alignas(16) __bf16 As[2][BM * 64];
  __shared__ alignas(16) __bf16 Bs[2][BN * 64];

  const int tid = threadIdx.x;
  const int lane = tid & 63;
  const int wave = tid >> 6;
  const int wr = wave / WN, wc = wave % WN;
  const int l15 = lane & 15;
  const int g = lane >> 4;

  int bx, by;
  if (MODE == 1 || MODE == 2) {
    // per-XCD 8x8 square over the 16 by x 32 bx grid (bijective, 512 blocks)
    const int bid = blockIdx.x;         // [0,512)
    const int x = bid & 7;              // XCD
    const int u = bid >> 3;             // [0,64)
    by = ((x >> 2) << 3) + (u >> 3);    // [0,16)
    bx = ((x & 3) << 3) + (u & 7);      // [0,32)
  } else {
    const int nwg = gridDim.x * gridDim.y;
    const int bid = blockIdx.y * gridDim.x + blockIdx.x;
    const int cpx = nwg >> 3;
    const int tswz = (bid & 7) * cpx + (bid >> 3);
    bx = tswz % gridDim.x;
    by = tswz / gridDim.x;
  }
  const int m0 = by * BM, n0 = bx * BN;

  f32x4 acc[M_rep][N_rep] = {};

  const int srcChunkElem = ((lane & 7) ^ (lane >> 3)) * 8;
  const int rowInWave = wave * 8 + (lane >> 3);

  const int NT = K >> 6;

  auto stage = [&](int buf, int kt) {
    const int k0 = kt << 6;
#pragma unroll
    for (int i = 0; i < nA; ++i) {
      int row = i * ROWS_PER_ISSUE + rowInWave;
      gload_lds16(A + (size_t)(m0 + row) * K + k0 + srcChunkElem,
                  &As[buf][(i * T + wave * 64) * 8]);
    }
#pragma unroll
    for (int i = 0; i < nB; ++i) {
      int row = i * ROWS_PER_ISSUE + rowInWave;
      gload_lds16(Bt + (size_t)(n0 + row) * K + k0 + srcChunkElem,
                  &Bs[buf][(i * T + wave * 64) * 8]);
    }
  };

  stage(0, 0);

  for (int kt = 0; kt < NT; ++kt) {
    const int cur = kt & 1;
    if (kt + 1 < NT) {
      stage(cur ^ 1, kt + 1);
      if constexpr (NISSUE == 8)
        asm volatile("s_waitcnt vmcnt(8)" ::: "memory");
      else if constexpr (NISSUE == 6)
        asm volatile("s_waitcnt vmcnt(6)" ::: "memory");
      else if constexpr (NISSUE == 5)
        asm volatile("s_waitcnt vmcnt(5)" ::: "memory");
      else if constexpr (NISSUE == 3)
        asm volatile("s_waitcnt vmcnt(3)" ::: "memory");
      else
        asm volatile("s_waitcnt vmcnt(0)" ::: "memory");
    } else {
      asm volatile("s_waitcnt vmcnt(0)" ::: "memory");
    }
    __builtin_amdgcn_s_barrier();

    const char* ab = (const char*)&As[cur][0];
    const char* bb = (const char*)&Bs[cur][0];
#pragma unroll
    for (int hh = 0; hh < 2; ++hh) {
      bf16x8 af[M_rep], bfv[N_rep];
#pragma unroll
      for (int m = 0; m < M_rep; ++m) {
        int ar = wr * (M_rep * 16) + m * 16 + l15;
        int chunk = ((4 * hh + g) ^ (lane & 7));
        af[m] = *(const bf16x8*)(ab + ar * 128 + chunk * 16);
      }
#pragma unroll
      for (int n = 0; n < N_rep; ++n) {
        int br = wc * (N_rep * 16) + n * 16 + l15;
        int chunk = ((4 * hh + g) ^ (lane & 7));
        bfv[n] = *(const bf16x8*)(bb + br * 128 + chunk * 16);
      }
      __builtin_amdgcn_s_setprio(1);
#pragma unroll
      for (int m = 0; m < M_rep; ++m)
#pragma unroll
        for (int n = 0; n < N_rep; ++n)
          acc[m][n] = __builtin_amdgcn_mfma_f32_16x16x32_bf16(af[m], bfv[n], acc[m][n], 0, 0, 0);
      __builtin_amdgcn_s_setprio(0);
    }
    __builtin_amdgcn_s_barrier();
  }

  // epilogue
#pragma unroll
  for (int m = 0; m < M_rep; ++m) {
    int row_l = wr * (M_rep * 16) + m * 16 + (g << 2);
#pragma unroll
    for (int n = 0; n < N_rep; ++n) {
      int col = n0 + wc * (N_rep * 16) + n * 16 + l15;
#pragma unroll
      for (int r = 0; r < 4; ++r) {
        int row = m0 + row_l + r;
        float v = acc[m][n][r];
        if (MODE != 1) {
          Cout[(size_t)row * N + col] = v;
        } else {
          int b = row >> 10, t = row & 1023;
          int sec = col >> 11;           // 0=q,1=k,2=v (per-lane)
          int c2 = col & 2047;
          int h = c2 >> 5, d = c2 & 31;
          float partner = __shfl_xor(v, 1);  // unconditional, before divergence
          if (sec < 2) {
            float rot = (d & 1) ? partner : -partner;
            float cs = cosT[t * 32 + d], sn = sinT[t * 32 + d];
            float o = v * cs + rot * sn;
            if (sec == 0) o *= 0.17677669529663687f;  // fold 1/sqrt(hd) into Q
            __bf16* dst = sec ? Ko : Qo;
            dst[((size_t)((b << 6) | h) * Tlen + t) * HD + d] = (__bf16)o;
          } else {
            Vto[((size_t)((b << 6) | h) * HD + d) * Tlen + t] = (__bf16)v;
          }
        }
      }
    }
  }
}

// ---------- flash attention: swapped QK^T, KVBLK=64, static softmax, kf prefetch ----
__launch_bounds__(256)
__global__ void k_attn(const __bf16* __restrict__ Q, const __bf16* __restrict__ Kmat,
                       const __bf16* __restrict__ Vt, __bf16* __restrict__ att) {
  __shared__ alignas(16) __bf16 P[4][32 * 72];
  const int tid = threadIdx.x;
  const int lane = tid & 63;
  const int w = tid >> 6;

  const int orig = blockIdx.y * gridDim.x + blockIdx.x;  // [0,1024)
  const int idx = orig >> 3;                             // [0,128)
  const int bh = (orig & 7) * 16 + (idx >> 3);           // 16 heads per XCD
  const int j = idx & 7;                                 // [0,8)

  const int qt = (w == 0) ? 2 * j : (w == 1) ? 2 * j + 1 : (w == 2) ? 30 - 2 * j : 31 - 2 * j;
  const int q0 = qt * 32;

  const __bf16* Qb = Q + (size_t)bh * Tlen * HD;
  const __bf16* Kb = Kmat + (size_t)bh * Tlen * HD;
  const __bf16* Vb = Vt + (size_t)bh * HD * Tlen;
  __bf16* Pw = &P[w][0];

  const int l15 = lane & 15;
  const int g = lane >> 4;
  const int lk8 = g * 8;

  bf16x8 qf[2];
#pragma unroll
  for (int m = 0; m < 2; ++m)
    qf[m] = *(const bf16x8*)(Qb + (size_t)(q0 + m * 16 + l15) * HD + lk8);

  f32x4 o[2][2] = {};
  float lsum[2] = {0.f, 0.f};

  const int nfull = q0 >> 6;

  bf16x8 kfA[4];
#pragma unroll
  for (int n = 0; n < 4; ++n)
    kfA[n] = *(const bf16x8*)(Kb + (size_t)(n * 16 + l15) * HD + lk8);

  for (int kt = 0; kt <= nfull; ++kt) {
    const int k0 = kt * 64;

    bf16x8 kfN[4] = {};
    if (kt < nfull) {
#pragma unroll
      for (int n = 0; n < 4; ++n)
        kfN[n] = *(const bf16x8*)(Kb + (size_t)(k0 + 64 + n * 16 + l15) * HD + lk8);
    }

    f32x4 st[4][2] = {};
#pragma unroll
    for (int n = 0; n < 4; ++n)
#pragma unroll
      for (int m = 0; m < 2; ++m)
        st[n][m] = __builtin_amdgcn_mfma_f32_16x16x32_bf16(kfA[n], qf[m], st[n][m], 0, 0, 0);

    bf16x8 vf[2][2];
#pragma unroll
    for (int nn = 0; nn < 2; ++nn)
#pragma unroll
      for (int c = 0; c < 2; ++c)
        vf[nn][c] = *(const bf16x8*)(Vb + (size_t)(nn * 16 + l15) * Tlen + k0 + c * 32 + lk8);

    if (kt == nfull) {
#pragma unroll
      for (int n = 0; n < 4; ++n)
#pragma unroll
        for (int m = 0; m < 2; ++m)
#pragma unroll
          for (int r = 0; r < 4; ++r) {
            int kk = k0 + n * 16 + 4 * g + r;
            int qq = q0 + m * 16 + l15;
            if (kk > qq) st[n][m][r] = -1e30f;
          }
    }

#pragma unroll
    for (int m = 0; m < 2; ++m) {
      float p[16];
      float ps = 0.f;
#pragma unroll
      for (int n = 0; n < 4; ++n)
#pragma unroll
        for (int r = 0; r < 4; ++r) {
          float pv = __expf(st[n][m][r]);
          p[n * 4 + r] = pv;
          ps += pv;
        }
      ps += __shfl_xor(ps, 16);
      ps += __shfl_xor(ps, 32);
      lsum[m] += ps;

#pragma unroll
      for (int n = 0; n < 4; ++n) {
        unsigned int u0 = ((unsigned int)bfbits(p[n * 4 + 1]) << 16) | bfbits(p[n * 4 + 0]);
        unsigned int u1 = ((unsigned int)bfbits(p[n * 4 + 3]) << 16) | bfbits(p[n * 4 + 2]);
        int base = (m * 16 + l15) * 72 + n * 16 + 4 * g;
        *(unsigned int*)&Pw[base] = u0;
        *(unsigned int*)&Pw[base + 2] = u1;
      }
    }

    bf16x8 pa[2][2];
#pragma unroll
    for (int m = 0; m < 2; ++m)
#pragma unroll
      for (int c = 0; c < 2; ++c)
        pa[m][c] = *(const bf16x8*)&Pw[(m * 16 + l15) * 72 + c * 32 + lk8];

#pragma unroll
    for (int m = 0; m < 2; ++m)
#pragma unroll
      for (int nn = 0; nn < 2; ++nn)
#pragma unroll
        for (int c = 0; c < 2; ++c)
          o[m][nn] = __builtin_amdgcn_mfma_f32_16x16x32_bf16(pa[m][c], vf[nn][c], o[m][nn], 0, 0, 0);

    if (kt < nfull) {
#pragma unroll
      for (int n = 0; n < 4; ++n) kfA[n] = kfN[n];
    }
  }

  const int b = bh >> 6;
  const int h = bh & 63;
#pragma unroll
  for (int m = 0; m < 2; ++m) {
#pragma unroll
    for (int r = 0; r < 4; ++r) {
      float ls = __shfl(lsum[m], (lane & 48) + ((lane >> 4) << 2) + r);
      float inv = 1.0f / ls;
      int t = q0 + m * 16 + 4 * g + r;
#pragma unroll
      for (int nn = 0; nn < 2; ++nn) {
        float ov = o[m][nn][r] * inv;
        att[((size_t)(b * Tlen + t)) * 2048 + h * 32 + nn * 16 + l15] = (__bf16)ov;
      }
    }
  }
}

// ---------- launch ----------

extern "C" void kernel_launch(void* const* d_in, const int* in_sizes, int n_in,
                              void* d_out, int out_size, void* d_ws, size_t ws_size,
                              hipStream_t stream) {
  const float* x = (const float*)d_in[0];
  const float* pos = (const float*)d_in[1];
  const float* w_attn = (const float*)d_in[2];
  const float* w_proj = (const float*)d_in[3];
  float* out = (float*)d_out;

  char* ws = (char*)d_ws;
  size_t off = 0;
  auto alloc = [&](size_t bytes) {
    void* p = ws + off;
    off = (off + bytes + 255) & ~(size_t)255;
    return p;
  };
  __bf16* xb  = (__bf16*)alloc(2048ull * 2048 * 2);
  __bf16* waT = (__bf16*)alloc(6144ull * 2048 * 2);
  __bf16* wpT = (__bf16*)alloc(2048ull * 2048 * 2);
  __bf16* Qb  = (__bf16*)alloc(2ull * 64 * 1024 * 32 * 2);
  __bf16* Kb  = (__bf16*)alloc(2ull * 64 * 1024 * 32 * 2);
  __bf16* Vtb = (__bf16*)alloc(2ull * 64 * 32 * 1024 * 2);
  __bf16* att = (__bf16*)alloc(2048ull * 2048 * 2);
  float* cosT = (float*)alloc(1024ull * 32 * 4);
  float* sinT = (float*)alloc(1024ull * 32 * 4);

  // fused staging
  k_stage<<<6272, 256, 0, stream>>>(x, xb, w_attn, waT, w_proj, wpT, pos, cosT, sinT);

  // qkv = xb @ waT^T (128x192 tile, 8 waves of 2x4, 512 blocks = 2/CU; 8x8 XCD square)
  k_gemm<128, 192, 2, 4, 1><<<512, 512, 0, stream>>>(
      xb, waT, 2048, 6144, 2048, nullptr, Qb, Kb, Vtb, cosT, sinT);

  k_attn<<<dim3(8, 128), 256, 0, stream>>>(Qb, Kb, Vtb, att);

  // out = att @ wpT^T (128x64, 8 waves of 2x4; 8x8 XCD square)
  k_gemm<128, 64, 2, 4, 2><<<512, 512, 0, stream>>>(
      att, wpT, 2048, 2048, 2048, out, nullptr, nullptr, nullptr, nullptr, nullptr);
}

// Round 18
// 149.952 us; speedup vs baseline: 1.0250x; 1.0250x over previous
//
#include <hip/hip_runtime.h>
#include <hip/hip_bf16.h>
#include <math.h>

typedef __attribute__((ext_vector_type(8))) __bf16 bf16x8;
typedef __attribute__((ext_vector_type(4))) __bf16 bf16x4;
typedef __attribute__((ext_vector_type(4))) float f32x4;

#define DEVINL static __device__ __forceinline__

static constexpr int Tlen = 1024;
static constexpr int HD = 32;

DEVINL void gload_lds16(const void* g, void* l) {
  __builtin_amdgcn_global_load_lds(
      (const __attribute__((address_space(1))) void*)g,
      (__attribute__((address_space(3))) void*)l, 16, 0, 0);
}

DEVINL unsigned short bfbits(float x) {
  __bf16 b = (__bf16)x;
  return __builtin_bit_cast(unsigned short, b);
}

// ---------- fused staging kernel: cvt | transpose(w_attn) | transpose(w_proj) | sincos ----
__global__ void k_stage(const float* __restrict__ x, __bf16* __restrict__ xb,
                        const float* __restrict__ w_attn, __bf16* __restrict__ waT,
                        const float* __restrict__ w_proj, __bf16* __restrict__ wpT,
                        const float* __restrict__ pos, float* __restrict__ cosT,
                        float* __restrict__ sinT) {
  const int bid = blockIdx.x;
  if (bid < 2048) {
    int i = (bid * 256 + threadIdx.x) * 8;
    const float4* p = (const float4*)(x + i);
    float4 a = p[0], b = p[1];
    bf16x8 v;
    v[0] = (__bf16)a.x; v[1] = (__bf16)a.y; v[2] = (__bf16)a.z; v[3] = (__bf16)a.w;
    v[4] = (__bf16)b.x; v[5] = (__bf16)b.y; v[6] = (__bf16)b.z; v[7] = (__bf16)b.w;
    *(bf16x8*)(xb + i) = v;
    return;
  }
  if (bid >= 6144) {
    int idx = (bid - 6144) * 256 + threadIdx.x;  // T*32
    int t = idx >> 5, d = idx & 31;
    float invf = powf(10000.0f, -(float)d * (1.0f / 32.0f));
    float ang = pos[t] * invf;
    cosT[idx] = cosf(ang);
    sinT[idx] = sinf(ang);
    return;
  }
  const float* w;
  __bf16* wt;
  int n0, k0, K, N;
  if (bid < 5120) {  // w_attn: 3072 blocks
    int t = bid - 2048;
    w = w_attn; wt = waT; K = 2048; N = 6144;
    n0 = (t % 96) * 64; k0 = (t / 96) * 64;
  } else {           // w_proj: 1024 blocks
    int t = bid - 5120;
    w = w_proj; wt = wpT; K = 2048; N = 2048;
    n0 = (t % 32) * 64; k0 = (t / 32) * 64;
  }
  __shared__ float tile[64][65];
  const int tx = threadIdx.x & 15;
  const int ty = threadIdx.x >> 4;
#pragma unroll
  for (int i = 0; i < 4; ++i) {
    float4 v = *(const float4*)&w[(size_t)(k0 + ty + i * 16) * N + n0 + tx * 4];
    tile[ty + i * 16][tx * 4 + 0] = v.x;
    tile[ty + i * 16][tx * 4 + 1] = v.y;
    tile[ty + i * 16][tx * 4 + 2] = v.z;
    tile[ty + i * 16][tx * 4 + 3] = v.w;
  }
  __syncthreads();
#pragma unroll
  for (int i = 0; i < 4; ++i) {
    int n = ty + i * 16;
    bf16x4 s;
#pragma unroll
    for (int j = 0; j < 4; ++j) s[j] = (__bf16)tile[tx * 4 + j][n];
    *(bf16x4*)&wt[(size_t)(n0 + n) * K + k0 + tx * 4] = s;
  }
}

// ---------- 2-phase dbuf GEMM template (counted vmcnt, chunk swizzle) ----------
// R14-exact best-measured configuration (150.0 us total).
// MODE 0: fp32 store, tswz 2D-grid mapping.
// MODE 1: RoPE epilogue, by-pair clustered 1D grid (XCD x owns by {2x,2x+1};
// A-panel 1 MB L2-resident per XCD).
template <int BM, int BN, int WM, int WN, int MODE>
__launch_bounds__(WM * WN * 64, 4)
__global__ void k_gemm(const __bf16* __restrict__ A, const __bf16* __restrict__ Bt,
                       int M, int N, int K, float* __restrict__ Cout,
                       __bf16* __restrict__ Qo, __bf16* __restrict__ Ko,
                       __bf16* __restrict__ Vto, const float* __restrict__ cosT,
                       const float* __restrict__ sinT) {
  constexpr int T = WM * WN * 64;
  constexpr int M_rep = BM / (WM * 16);
  constexpr int N_rep = BN / (WN * 16);
  constexpr int nA = (BM * 128) / (T * 16);
  constexpr int nB = (BN * 128) / (T * 16);
  constexpr int NISSUE = nA + nB;
  constexpr int ROWS_PER_ISSUE = T / 8;

  __shared__ alignas(16) __bf16 As[2][BM * 64];
  __shared__ alignas(16) __bf16 Bs[2][BN * 64];

  const int tid = threadIdx.x;
  const int lane = tid & 63;
  const int wave = tid >> 6;
  const int wr = wave / WN, wc = wave % WN;
  const int l15 = lane & 15;
  const int g = lane >> 4;

  int bx, by;
  if (MODE == 1) {
    // by-pair clustered: XCD x owns by in {2x, 2x+1}
    const int bid = blockIdx.x;         // [0,512)
    const int u = bid >> 3;             // [0,64)
    by = 2 * (bid & 7) + (u & 1);       // [0,16)
    bx = u >> 1;                        // [0,32)
  } else {
    const int nwg = gridDim.x * gridDim.y;
    const int bid = blockIdx.y * gridDim.x + blockIdx.x;
    const int cpx = nwg >> 3;
    const int tswz = (bid & 7) * cpx + (bid >> 3);
    bx = tswz % gridDim.x;
    by = tswz / gridDim.x;
  }
  const int m0 = by * BM, n0 = bx * BN;

  f32x4 acc[M_rep][N_rep] = {};

  const int srcChunkElem = ((lane & 7) ^ (lane >> 3)) * 8;
  const int rowInWave = wave * 8 + (lane >> 3);

  const int NT = K >> 6;

  auto stage = [&](int buf, int kt) {
    const int k0 = kt << 6;
#pragma unroll
    for (int i = 0; i < nA; ++i) {
      int row = i * ROWS_PER_ISSUE + rowInWave;
      gload_lds16(A + (size_t)(m0 + row) * K + k0 + srcChunkElem,
                  &As[buf][(i * T + wave * 64) * 8]);
    }
#pragma unroll
    for (int i = 0; i < nB; ++i) {
      int row = i * ROWS_PER_ISSUE + rowInWave;
      gload_lds16(Bt + (size_t)(n0 + row) * K + k0 + srcChunkElem,
                  &Bs[buf][(i * T + wave * 64) * 8]);
    }
  };

  stage(0, 0);

  for (int kt = 0; kt < NT; ++kt) {
    const int cur = kt & 1;
    if (kt + 1 < NT) {
      stage(cur ^ 1, kt + 1);
      if constexpr (NISSUE == 8)
        asm volatile("s_waitcnt vmcnt(8)" ::: "memory");
      else if constexpr (NISSUE == 6)
        asm volatile("s_waitcnt vmcnt(6)" ::: "memory");
      else if constexpr (NISSUE == 5)
        asm volatile("s_waitcnt vmcnt(5)" ::: "memory");
      else if constexpr (NISSUE == 3)
        asm volatile("s_waitcnt vmcnt(3)" ::: "memory");
      else
        asm volatile("s_waitcnt vmcnt(0)" ::: "memory");
    } else {
      asm volatile("s_waitcnt vmcnt(0)" ::: "memory");
    }
    __builtin_amdgcn_s_barrier();

    const char* ab = (const char*)&As[cur][0];
    const char* bb = (const char*)&Bs[cur][0];
#pragma unroll
    for (int hh = 0; hh < 2; ++hh) {
      bf16x8 af[M_rep], bfv[N_rep];
#pragma unroll
      for (int m = 0; m < M_rep; ++m) {
        int ar = wr * (M_rep * 16) + m * 16 + l15;
        int chunk = ((4 * hh + g) ^ (lane & 7));
        af[m] = *(const bf16x8*)(ab + ar * 128 + chunk * 16);
      }
#pragma unroll
      for (int n = 0; n < N_rep; ++n) {
        int br = wc * (N_rep * 16) + n * 16 + l15;
        int chunk = ((4 * hh + g) ^ (lane & 7));
        bfv[n] = *(const bf16x8*)(bb + br * 128 + chunk * 16);
      }
      __builtin_amdgcn_s_setprio(1);
#pragma unroll
      for (int m = 0; m < M_rep; ++m)
#pragma unroll
        for (int n = 0; n < N_rep; ++n)
          acc[m][n] = __builtin_amdgcn_mfma_f32_16x16x32_bf16(af[m], bfv[n], acc[m][n], 0, 0, 0);
      __builtin_amdgcn_s_setprio(0);
    }
    __builtin_amdgcn_s_barrier();
  }

  // epilogue
#pragma unroll
  for (int m = 0; m < M_rep; ++m) {
    int row_l = wr * (M_rep * 16) + m * 16 + (g << 2);
#pragma unroll
    for (int n = 0; n < N_rep; ++n) {
      int col = n0 + wc * (N_rep * 16) + n * 16 + l15;
#pragma unroll
      for (int r = 0; r < 4; ++r) {
        int row = m0 + row_l + r;
        float v = acc[m][n][r];
        if (MODE == 0) {
          Cout[(size_t)row * N + col] = v;
        } else {
          int b = row >> 10, t = row & 1023;
          int sec = col >> 11;           // 0=q,1=k,2=v (per-lane)
          int c2 = col & 2047;
          int h = c2 >> 5, d = c2 & 31;
          float partner = __shfl_xor(v, 1);  // unconditional, before divergence
          if (sec < 2) {
            float rot = (d & 1) ? partner : -partner;
            float cs = cosT[t * 32 + d], sn = sinT[t * 32 + d];
            float o = v * cs + rot * sn;
            if (sec == 0) o *= 0.17677669529663687f;  // fold 1/sqrt(hd) into Q
            __bf16* dst = sec ? Ko : Qo;
            dst[((size_t)((b << 6) | h) * Tlen + t) * HD + d] = (__bf16)o;
          } else {
            Vto[((size_t)((b << 6) | h) * HD + d) * Tlen + t] = (__bf16)v;
          }
        }
      }
    }
  }
}

// ---------- flash attention: swapped QK^T, KVBLK=64, static softmax, kf prefetch ----
__launch_bounds__(256)
__global__ void k_attn(const __bf16* __restrict__ Q, const __bf16* __restrict__ Kmat,
                       const __bf16* __restrict__ Vt, __bf16* __restrict__ att) {
  __shared__ alignas(16) __bf16 P[4][32 * 72];
  const int tid = threadIdx.x;
  const int lane = tid & 63;
  const int w = tid >> 6;

  const int orig = blockIdx.y * gridDim.x + blockIdx.x;  // [0,1024)
  const int idx = orig >> 3;                             // [0,128)
  const int bh = (orig & 7) * 16 + (idx >> 3);           // 16 heads per XCD
  const int j = idx & 7;                                 // [0,8)

  const int qt = (w == 0) ? 2 * j : (w == 1) ? 2 * j + 1 : (w == 2) ? 30 - 2 * j : 31 - 2 * j;
  const int q0 = qt * 32;

  const __bf16* Qb = Q + (size_t)bh * Tlen * HD;
  const __bf16* Kb = Kmat + (size_t)bh * Tlen * HD;
  const __bf16* Vb = Vt + (size_t)bh * HD * Tlen;
  __bf16* Pw = &P[w][0];

  const int l15 = lane & 15;
  const int g = lane >> 4;
  const int lk8 = g * 8;

  bf16x8 qf[2];
#pragma unroll
  for (int m = 0; m < 2; ++m)
    qf[m] = *(const bf16x8*)(Qb + (size_t)(q0 + m * 16 + l15) * HD + lk8);

  f32x4 o[2][2] = {};
  float lsum[2] = {0.f, 0.f};

  const int nfull = q0 >> 6;

  bf16x8 kfA[4];
#pragma unroll
  for (int n = 0; n < 4; ++n)
    kfA[n] = *(const bf16x8*)(Kb + (size_t)(n * 16 + l15) * HD + lk8);

  for (int kt = 0; kt <= nfull; ++kt) {
    const int k0 = kt * 64;

    bf16x8 kfN[4] = {};
    if (kt < nfull) {
#pragma unroll
      for (int n = 0; n < 4; ++n)
        kfN[n] = *(const bf16x8*)(Kb + (size_t)(k0 + 64 + n * 16 + l15) * HD + lk8);
    }

    f32x4 st[4][2] = {};
#pragma unroll
    for (int n = 0; n < 4; ++n)
#pragma unroll
      for (int m = 0; m < 2; ++m)
        st[n][m] = __builtin_amdgcn_mfma_f32_16x16x32_bf16(kfA[n], qf[m], st[n][m], 0, 0, 0);

    bf16x8 vf[2][2];
#pragma unroll
    for (int nn = 0; nn < 2; ++nn)
#pragma unroll
      for (int c = 0; c < 2; ++c)
        vf[nn][c] = *(const bf16x8*)(Vb + (size_t)(nn * 16 + l15) * Tlen + k0 + c * 32 + lk8);

    if (kt == nfull) {
#pragma unroll
      for (int n = 0; n < 4; ++n)
#pragma unroll
        for (int m = 0; m < 2; ++m)
#pragma unroll
          for (int r = 0; r < 4; ++r) {
            int kk = k0 + n * 16 + 4 * g + r;
            int qq = q0 + m * 16 + l15;
            if (kk > qq) st[n][m][r] = -1e30f;
          }
    }

#pragma unroll
    for (int m = 0; m < 2; ++m) {
      float p[16];
      float ps = 0.f;
#pragma unroll
      for (int n = 0; n < 4; ++n)
#pragma unroll
        for (int r = 0; r < 4; ++r) {
          float pv = __expf(st[n][m][r]);
          p[n * 4 + r] = pv;
          ps += pv;
        }
      ps += __shfl_xor(ps, 16);
      ps += __shfl_xor(ps, 32);
      lsum[m] += ps;

#pragma unroll
      for (int n = 0; n < 4; ++n) {
        unsigned int u0 = ((unsigned int)bfbits(p[n * 4 + 1]) << 16) | bfbits(p[n * 4 + 0]);
        unsigned int u1 = ((unsigned int)bfbits(p[n * 4 + 3]) << 16) | bfbits(p[n * 4 + 2]);
        int base = (m * 16 + l15) * 72 + n * 16 + 4 * g;
        *(unsigned int*)&Pw[base] = u0;
        *(unsigned int*)&Pw[base + 2] = u1;
      }
    }

    bf16x8 pa[2][2];
#pragma unroll
    for (int m = 0; m < 2; ++m)
#pragma unroll
      for (int c = 0; c < 2; ++c)
        pa[m][c] = *(const bf16x8*)&Pw[(m * 16 + l15) * 72 + c * 32 + lk8];

#pragma unroll
    for (int m = 0; m < 2; ++m)
#pragma unroll
      for (int nn = 0; nn < 2; ++nn)
#pragma unroll
        for (int c = 0; c < 2; ++c)
          o[m][nn] = __builtin_amdgcn_mfma_f32_16x16x32_bf16(pa[m][c], vf[nn][c], o[m][nn], 0, 0, 0);

    if (kt < nfull) {
#pragma unroll
      for (int n = 0; n < 4; ++n) kfA[n] = kfN[n];
    }
  }

  const int b = bh >> 6;
  const int h = bh & 63;
#pragma unroll
  for (int m = 0; m < 2; ++m) {
#pragma unroll
    for (int r = 0; r < 4; ++r) {
      float ls = __shfl(lsum[m], (lane & 48) + ((lane >> 4) << 2) + r);
      float inv = 1.0f / ls;
      int t = q0 + m * 16 + 4 * g + r;
#pragma unroll
      for (int nn = 0; nn < 2; ++nn) {
        float ov = o[m][nn][r] * inv;
        att[((size_t)(b * Tlen + t)) * 2048 + h * 32 + nn * 16 + l15] = (__bf16)ov;
      }
    }
  }
}

// ---------- launch ----------

extern "C" void kernel_launch(void* const* d_in, const int* in_sizes, int n_in,
                              void* d_out, int out_size, void* d_ws, size_t ws_size,
                              hipStream_t stream) {
  const float* x = (const float*)d_in[0];
  const float* pos = (const float*)d_in[1];
  const float* w_attn = (const float*)d_in[2];
  const float* w_proj = (const float*)d_in[3];
  float* out = (float*)d_out;

  char* ws = (char*)d_ws;
  size_t off = 0;
  auto alloc = [&](size_t bytes) {
    void* p = ws + off;
    off = (off + bytes + 255) & ~(size_t)255;
    return p;
  };
  __bf16* xb  = (__bf16*)alloc(2048ull * 2048 * 2);
  __bf16* waT = (__bf16*)alloc(6144ull * 2048 * 2);
  __bf16* wpT = (__bf16*)alloc(2048ull * 2048 * 2);
  __bf16* Qb  = (__bf16*)alloc(2ull * 64 * 1024 * 32 * 2);
  __bf16* Kb  = (__bf16*)alloc(2ull * 64 * 1024 * 32 * 2);
  __bf16* Vtb = (__bf16*)alloc(2ull * 64 * 32 * 1024 * 2);
  __bf16* att = (__bf16*)alloc(2048ull * 2048 * 2);
  float* cosT = (float*)alloc(1024ull * 32 * 4);
  float* sinT = (float*)alloc(1024ull * 32 * 4);

  // fused staging
  k_stage<<<6272, 256, 0, stream>>>(x, xb, w_attn, waT, w_proj, wpT, pos, cosT, sinT);

  // qkv = xb @ waT^T (128x192 tile, 8 waves of 2x4, 512 blocks = 2/CU, 4 waves/SIMD)
  k_gemm<128, 192, 2, 4, 1><<<512, 512, 0, stream>>>(
      xb, waT, 2048, 6144, 2048, nullptr, Qb, Kb, Vtb, cosT, sinT);

  k_attn<<<dim3(8, 128), 256, 0, stream>>>(Qb, Kb, Vtb, att);

  // out = att @ wpT^T (128x64, 8 waves of 2x4, tswz 2D grid — R14 measured-best)
  k_gemm<128, 64, 2, 4, 0><<<dim3(32, 16), 512, 0, stream>>>(
      att, wpT, 2048, 2048, 2048, out, nullptr, nullptr, nullptr, nullptr, nullptr);
}